// Round 6
// baseline (1105.341 us; speedup 1.0000x reference)
//
#include <hip/hip_runtime.h>
#include <stdint.h>

// ---------------- problem constants ----------------
#define NFRAMES 2
#define NPROP   16384
#define NROWS   (NFRAMES * NPROP)        // 32768 (= M of all GEMMs)
#define DIN_    1024
#define HDIM    512
#define NCLS    11
#define LRLD    128                      // rows of lr^T: [logits(11) | reg(99) | pad]
#define NBINS   8192
#define CAP     2048                     // gathered candidate capacity per frame
#define TGT     1024                     // target top-N for NMS scan
#define KKEEP   100
#define SCORE_T 0.05f
#define NMS_T   0.5f
#define CLIPV   4.135166556742356f       // log(1000/16)

// ---------------- workspace layout (bytes) ----------------
// Reuse discipline (stream-ordered):
//   OFF_A: x^T half (gemm1a) -> x^T half (gemm1b) -> h2^T (gemm2 out)
//   OFF_B: h1^T
#define OFF_A       0ULL                           // 64 MB
#define OFF_B       67108864ULL                    // 64 MB
#define OFF_LRT     134217728ULL                   // 128*32768 f32 = 16 MB
#define OFF_WCAT    150994944ULL                   // 512*128 f32
#define OFF_BCAT    151257088ULL                   // 128 f32 (padded)
#define OFF_SCORES  151258112ULL                   // 32768*10 f32
#define OFF_HIST    152568832ULL                   // 2*8192 i32
#define OFF_GCNT    152634368ULL                   // 2 i32
#define OFF_TAU     152634376ULL                   // 2 i32
#define OFF_GKEYS   152634624ULL                   // 2*2048 u64
#define WS_NEEDED   152700160ULL

// ---------------- box decode (must match reference float ops) ----------------
__device__ __forceinline__ void decodev(const float* __restrict__ prop,
                                        float g0, float g1, float g2, float g3,
                                        float& x1, float& y1, float& x2, float& y2) {
    float w  = prop[2] - prop[0];
    float h  = prop[3] - prop[1];
    float cx = prop[0] + 0.5f * w;
    float cy = prop[1] + 0.5f * h;
    float dx = g0 / 10.0f;
    float dy = g1 / 10.0f;
    float dw = fminf(g2 / 5.0f, CLIPV);
    float dh = fminf(g3 / 5.0f, CLIPV);
    float pcx = dx * w + cx;
    float pcy = dy * h + cy;
    float pw  = expf(dw) * w;
    float ph  = expf(dh) * h;
    x1 = pcx - 0.5f * pw;
    y1 = pcy - 0.5f * ph;
    x2 = pcx + 0.5f * pw;
    y2 = pcy + 0.5f * ph;
}

// ---------------- async global->LDS (16B per lane; wave-uniform LDS base) ----------------
__device__ __forceinline__ void async_cp16(const float* g, char* lds) {
    __builtin_amdgcn_global_load_lds((const __attribute__((address_space(1))) void*)g,
                                     (__attribute__((address_space(3))) void*)lds,
                                     16, 0, 0);
}

// ---------------- 64x64 tile transpose of one K-half of x ----------------
// x [NROWS][DIN_] cols [koff, koff+512) -> xT [512][NROWS]
__global__ __launch_bounds__(256) void transpose_half(const float* __restrict__ x,
                                                      float* __restrict__ xT,
                                                      int koff) {
    __shared__ float t[64][65];
    const int mb = blockIdx.x * 64;
    const int kb = blockIdx.y * 64;
    const int tid = threadIdx.x;
    const int r  = tid >> 4;           // 0..15
    const int c4 = (tid & 15) * 4;
#pragma unroll
    for (int i = 0; i < 4; ++i) {
        float4 v = *(const float4*)(x + (size_t)(mb + r + i * 16) * DIN_ + koff + kb + c4);
        t[r + i * 16][c4 + 0] = v.x;
        t[r + i * 16][c4 + 1] = v.y;
        t[r + i * 16][c4 + 2] = v.z;
        t[r + i * 16][c4 + 3] = v.w;
    }
    __syncthreads();
#pragma unroll
    for (int i = 0; i < 4; ++i) {
        float4 v;
        v.x = t[c4 + 0][r + i * 16];
        v.y = t[c4 + 1][r + i * 16];
        v.z = t[c4 + 2][r + i * 16];
        v.w = t[c4 + 3][r + i * 16];
        *(float4*)(xT + (size_t)(kb + r + i * 16) * NROWS + mb + c4) = v;
    }
}

// ---------------- fp32 GEMM: CT[N][M] (+)= (AT[K][M])^T' x B[K][N], 128x128 tile, 8x8 micro ----
// R5: async global_load_lds double-buffer, ONE barrier per K-stage, no VGPR staging.
// Loads for stage k+1 issued before stage k's 512 FMAs -> vmcnt drain at the barrier
// finds them complete (removes the ~30% stall of the VGPR-roundtrip staging).
// Both operands k-major => each lane's 16B chunk lands contiguous (chunk id == tid).
__global__ __launch_bounds__(256) void gemm_nt(const float* __restrict__ AT,
                                               const float* __restrict__ B,
                                               const float* __restrict__ bias,
                                               float* __restrict__ CT,
                                               int K, int N, int accum, int relu) {
    __shared__ float As[2][8][128];   // 4 KB each buffer
    __shared__ float Bs[2][8][128];
    const int tid = threadIdx.x;
    const size_t M = NROWS;
    const int m0 = blockIdx.x * 128;
    const int n0 = blockIdx.y * 128;
    const int tx = tid & 15, ty = tid >> 4;
    const int w  = tid >> 6;
    // staging: chunk id == tid; 16B per lane; tile = 8 k-rows x 128 cols
    const int ckk  = tid >> 5;           // 0..7
    const int ccol = (tid & 31) * 4;     // 0..124
    const float* gA = AT + (size_t)ckk * M + m0 + ccol;
    const float* gB = B  + (size_t)ckk * N + n0 + ccol;
    char* ldsA[2] = {(char*)&As[0][0][0] + w * 1024, (char*)&As[1][0][0] + w * 1024};
    char* ldsB[2] = {(char*)&Bs[0][0][0] + w * 1024, (char*)&Bs[1][0][0] + w * 1024};

    float acc[8][8];
    if (accum) {
#pragma unroll
        for (int j = 0; j < 8; ++j) {
            int n = n0 + ((j < 4) ? tx * 4 + j : 64 + tx * 4 + (j - 4));
#pragma unroll
            for (int g = 0; g < 2; ++g) {
                float4 v = *(const float4*)(CT + (size_t)n * M + m0 + g * 64 + ty * 4);
                acc[g * 4 + 0][j] = v.x; acc[g * 4 + 1][j] = v.y;
                acc[g * 4 + 2][j] = v.z; acc[g * 4 + 3][j] = v.w;
            }
        }
    } else {
#pragma unroll
        for (int i = 0; i < 8; ++i)
#pragma unroll
            for (int j = 0; j < 8; ++j) acc[i][j] = 0.f;
    }

    // prologue: stage 0
    async_cp16(gA, ldsA[0]);
    async_cp16(gB, ldsB[0]);
    __builtin_amdgcn_s_waitcnt(0);
    __syncthreads();

    int p = 0;
    for (int k0 = 0; k0 < K; k0 += 8) {
        if (k0 + 8 < K) {               // issue next stage into the other buffer
            async_cp16(gA + (size_t)(k0 + 8) * M, ldsA[p ^ 1]);
            async_cp16(gB + (size_t)(k0 + 8) * N, ldsB[p ^ 1]);
        }
#pragma unroll
        for (int kk = 0; kk < 8; ++kk) {
            float4 a0 = *(const float4*)&As[p][kk][ty * 4];
            float4 a1 = *(const float4*)&As[p][kk][64 + ty * 4];
            float4 b0 = *(const float4*)&Bs[p][kk][tx * 4];
            float4 b1 = *(const float4*)&Bs[p][kk][64 + tx * 4];
            float ar[8] = {a0.x, a0.y, a0.z, a0.w, a1.x, a1.y, a1.z, a1.w};
            float br[8] = {b0.x, b0.y, b0.z, b0.w, b1.x, b1.y, b1.z, b1.w};
#pragma unroll
            for (int i = 0; i < 8; ++i)
#pragma unroll
                for (int j = 0; j < 8; ++j) acc[i][j] += ar[i] * br[j];
        }
        __builtin_amdgcn_s_waitcnt(0);  // async loads for next stage done
        __syncthreads();                // everyone finished reading buf[p]
        p ^= 1;
    }

#pragma unroll
    for (int j = 0; j < 8; ++j) {
        int n = n0 + ((j < 4) ? tx * 4 + j : 64 + tx * 4 + (j - 4));
        float bv = bias ? bias[n] : 0.f;
#pragma unroll
        for (int g = 0; g < 2; ++g) {
            float4 v;
            v.x = acc[g * 4 + 0][j] + bv;
            v.y = acc[g * 4 + 1][j] + bv;
            v.z = acc[g * 4 + 2][j] + bv;
            v.w = acc[g * 4 + 3][j] + bv;
            if (relu) {
                v.x = fmaxf(v.x, 0.f); v.y = fmaxf(v.y, 0.f);
                v.z = fmaxf(v.z, 0.f); v.w = fmaxf(v.w, 0.f);
            }
            *(float4*)(CT + (size_t)n * M + m0 + g * 64 + ty * 4) = v;
        }
    }
}

// ---------------- concat wc|wr into [512][128] + zero hist/gcount/tau ----------------
__global__ void concat_w(const float* __restrict__ wc, const float* __restrict__ bc,
                         const float* __restrict__ wr, const float* __restrict__ br,
                         float* __restrict__ wcat, float* __restrict__ bcat,
                         int* __restrict__ hist, int* __restrict__ gcnt4) {
    int gid = blockIdx.x * 256 + threadIdx.x;
    if (gid >= HDIM * LRLD) return;
    if (gid < NFRAMES * NBINS) hist[gid] = 0;
    if (gid < 4) gcnt4[gid] = 0;          // gcount[2] + taubin[2] (contiguous)
    int k = gid >> 7, j = gid & 127;
    float v = 0.f;
    if (j < 11)       v = wc[k * 11 + j];
    else if (j < 110) v = wr[k * 99 + (j - 11)];
    wcat[gid] = v;
    if (k == 0) {
        float b = 0.f;
        if (j < 11)       b = bc[j];
        else if (j < 110) b = br[j - 11];
        bcat[j] = b;
    }
}

// ---------------- softmax + score histogram (reads lr^T: fully coalesced) ----------------
__global__ __launch_bounds__(256) void softmax_hist(const float* __restrict__ lrT,
                                                    float* __restrict__ scores,
                                                    int* __restrict__ hist) {
    __shared__ int lh[NBINS];   // 32 KB
    const int t = threadIdx.x;
    for (int i = t; i < NBINS; i += 256) lh[i] = 0;
    __syncthreads();

    const int r = blockIdx.x * 256 + t;
    float l[NCLS];
#pragma unroll
    for (int j = 0; j < NCLS; ++j) l[j] = lrT[(size_t)j * NROWS + r];
    float m = l[0];
#pragma unroll
    for (int j = 1; j < NCLS; ++j) m = fmaxf(m, l[j]);
    float e[NCLS]; float s = 0.f;
#pragma unroll
    for (int j = 0; j < NCLS; ++j) { e[j] = expf(l[j] - m); s += e[j]; }
#pragma unroll
    for (int c = 1; c < NCLS; ++c) {
        float p = e[c] / s;
        scores[(size_t)r * 10 + (c - 1)] = p;
        if (p > SCORE_T) {
            int bin = (int)(p * (float)NBINS);
            bin = min(max(bin, 0), NBINS - 1);
            atomicAdd(&lh[bin], 1);
        }
    }
    __syncthreads();
    const int b = (blockIdx.x * 256) >> 14;
    for (int i = t; i < NBINS; i += 256) {
        int c = lh[i];
        if (c) atomicAdd(&hist[b * NBINS + i], c);
    }
}

// ---------------- find histogram bin threshold covering top >= TGT ----------------
__global__ __launch_bounds__(1024) void select_tau(const int* __restrict__ hist,
                                                   int* __restrict__ taubin) {
    __shared__ int seg[1024];
    __shared__ int best;
    const int b = blockIdx.x, t = threadIdx.x;
    if (t == 0) best = 0;
    const int base = t * 8;
    int loc[8];
    int s = 0;
#pragma unroll
    for (int i = 7; i >= 0; --i) {
        s += hist[b * NBINS + base + i];
        loc[i] = s;
    }
    seg[t] = s;
    __syncthreads();
    for (int off = 1; off < 1024; off <<= 1) {
        int v = (t + off < 1024) ? seg[t + off] : 0;
        __syncthreads();
        seg[t] += v;
        __syncthreads();
    }
    const int above = (t + 1 < 1024) ? seg[t + 1] : 0;
    int bmax = -1;
#pragma unroll
    for (int i = 0; i < 8; ++i) {
        if (loc[i] + above >= TGT) bmax = base + i;
    }
    if (bmax >= 0) atomicMax(&best, bmax);
    __syncthreads();
    if (t == 0) taubin[b] = best;
}

// ---------------- gather top candidates as sortable keys ----------------
__global__ void gather_cand(const float* __restrict__ scores,
                            const float* __restrict__ lrT,
                            const float* __restrict__ proposals,
                            const int* __restrict__ taubin,
                            int* __restrict__ gcount,
                            unsigned long long* __restrict__ gkeys) {
    int gid = blockIdx.x * 256 + threadIdx.x;
    if (gid >= NROWS * 10) return;
    int r  = gid / 10;
    int ci = gid - r * 10;          // class-1
    int b  = r >> 14;
    float p = scores[gid];
    int bin = (int)(p * (float)NBINS);
    bin = min(max(bin, 0), NBINS - 1);
    if (bin < taubin[b]) return;
    if (!(p > SCORE_T)) return;
    const float* rb = lrT + (size_t)(11 + (ci + 1) * 9) * NROWS + r;
    float x1, y1, x2, y2;
    decodev(proposals + (size_t)r * 9,
            rb[0], rb[(size_t)NROWS], rb[2 * (size_t)NROWS], rb[3 * (size_t)NROWS],
            x1, y1, x2, y2);
    if (!((x2 - x1) >= 0.01f && (y2 - y1) >= 0.01f)) return;
    int pos = atomicAdd(&gcount[b], 1);
    if (pos < CAP) {
        unsigned int sb   = __float_as_uint(p);                 // p > 0 => order-preserving
        unsigned int cand = (unsigned)(r - b * NPROP) * 10u + (unsigned)ci;
        gkeys[(size_t)b * CAP + pos] =
            ((unsigned long long)(0xFFFFFFFFu - sb) << 32) | (unsigned long long)cand;
    }
}

// ---------------- bitonic sort of CAP keys per frame ----------------
__global__ __launch_bounds__(1024) void sort_cand(int* __restrict__ gcount,
                                                  unsigned long long* __restrict__ gkeys) {
    __shared__ unsigned long long sk[CAP];
    int b = blockIdx.x, tid = threadIdx.x;
    int gc = gcount[b]; if (gc > CAP) gc = CAP;
    for (int i = tid; i < CAP; i += 1024)
        sk[i] = (i < gc) ? gkeys[(size_t)b * CAP + i] : ~0ULL;
    __syncthreads();
    for (int k = 2; k <= CAP; k <<= 1) {
        for (int j = k >> 1; j > 0; j >>= 1) {
            for (int i = tid; i < CAP; i += 1024) {
                int ixj = i ^ j;
                if (ixj > i) {
                    bool up = ((i & k) == 0);
                    unsigned long long a = sk[i], c = sk[ixj];
                    if ((a > c) == up) { sk[i] = c; sk[ixj] = a; }
                }
            }
            __syncthreads();
        }
    }
    for (int i = tid; i < CAP; i += 1024)
        gkeys[(size_t)b * CAP + i] = sk[i];
    if (tid == 0 && gcount[b] > CAP) gcount[b] = CAP;
}

// ---------------- serial greedy NMS scan + output ----------------
__global__ __launch_bounds__(64) void nms_out(const unsigned long long* __restrict__ gkeys,
                                              const int* __restrict__ gcount,
                                              const float* __restrict__ scores,
                                              const float* __restrict__ lrT,
                                              const float* __restrict__ proposals,
                                              float* __restrict__ out) {
    int b = blockIdx.x, tid = threadIdx.x;
    __shared__ unsigned long long skeys[CAP];   // 16 KB: entire sorted list
    __shared__ float kbox[KKEEP][4];
    __shared__ int   kcls[KKEEP];
    __shared__ int   kcand[KKEEP];
    __shared__ int   kcount;
    if (tid == 0) kcount = 0;
    int gc = min(gcount[b], CAP);
    for (int i = tid; i < gc; i += 64)
        skeys[i] = gkeys[(size_t)b * CAP + i];
    __syncthreads();
    for (int ptr = 0; ptr < gc; ++ptr) {
        __syncthreads();
        int kc = kcount;
        if (kc >= KKEEP) break;
        unsigned long long key = skeys[ptr];
        unsigned int cand = (unsigned int)(key & 0xFFFFFFFFULL);
        int n = cand / 10;
        int c = (int)(cand - n * 10) + 1;
        int r = b * NPROP + n;
        const float* rb = lrT + (size_t)(11 + c * 9) * NROWS + r;
        float x1, y1, x2, y2;
        decodev(proposals + (size_t)r * 9,
                rb[0], rb[(size_t)NROWS], rb[2 * (size_t)NROWS], rb[3 * (size_t)NROWS],
                x1, y1, x2, y2);
        int sup = 0;
        for (int q = tid; q < kc; q += 64) {
            if (kcls[q] == c) {
                float xx1 = fmaxf(x1, kbox[q][0]);
                float yy1 = fmaxf(y1, kbox[q][1]);
                float xx2 = fminf(x2, kbox[q][2]);
                float yy2 = fminf(y2, kbox[q][3]);
                float inter = fmaxf(xx2 - xx1, 0.f) * fmaxf(yy2 - yy1, 0.f);
                float aa = (kbox[q][2] - kbox[q][0]) * (kbox[q][3] - kbox[q][1]);
                float ab = (x2 - x1) * (y2 - y1);
                float iou = inter / (aa + ab - inter + 1e-9f);
                if (iou > NMS_T) sup = 1;
            }
        }
        if (!__any(sup)) {
            if (tid == 0) {
                kbox[kc][0] = x1; kbox[kc][1] = y1; kbox[kc][2] = x2; kbox[kc][3] = y2;
                kcls[kc] = c; kcand[kc] = (int)cand; kcount = kc + 1;
            }
        }
    }
    __syncthreads();
    int kc = min(kcount, KKEEP);
    for (int k = tid; k < KKEEP; k += 64) {
        int cand = (k < kc) ? kcand[k] : 0;
        int n = cand / 10;
        int c = cand - n * 10 + 1;
        int r = b * NPROP + n;
        const float* prop = proposals + (size_t)r * 9;
        const float* rb = lrT + (size_t)(11 + c * 9) * NROWS + r;
        float x1, y1, x2, y2;
        decodev(prop, rb[0], rb[(size_t)NROWS], rb[2 * (size_t)NROWS], rb[3 * (size_t)NROWS],
                x1, y1, x2, y2);
        float* ob = out + ((size_t)b * KKEEP + k) * 9;
        ob[0] = x1; ob[1] = y1; ob[2] = x2; ob[3] = y2;
#pragma unroll
        for (int j = 0; j < 5; ++j) ob[4 + j] = prop[4 + j] + rb[(size_t)(4 + j) * NROWS];
        out[NFRAMES * KKEEP * 9 + b * KKEEP + k] =
            (k < kc) ? scores[(size_t)r * 10 + (c - 1)] : 0.f;
        out[NFRAMES * KKEEP * 9 + NFRAMES * KKEEP + b * KKEEP + k] =
            (k < kc) ? (float)c : -1.0f;
    }
}

// ---------------- host launch ----------------
extern "C" void kernel_launch(void* const* d_in, const int* in_sizes, int n_in,
                              void* d_out, int out_size, void* d_ws, size_t ws_size,
                              hipStream_t stream) {
    (void)in_sizes; (void)n_in; (void)out_size;
    if (ws_size < WS_NEEDED) return;

    const float* x         = (const float*)d_in[0];
    const float* proposals = (const float*)d_in[1];
    const float* w1        = (const float*)d_in[2];
    const float* b1        = (const float*)d_in[3];
    const float* w2        = (const float*)d_in[4];
    const float* b2        = (const float*)d_in[5];
    const float* wc        = (const float*)d_in[6];
    const float* bc        = (const float*)d_in[7];
    const float* wr        = (const float*)d_in[8];
    const float* br        = (const float*)d_in[9];
    float* out = (float*)d_out;

    char* ws = (char*)d_ws;
    float* bufA   = (float*)(ws + OFF_A);     // xT halves, then h2T
    float* h1T    = (float*)(ws + OFF_B);
    float* lrT    = (float*)(ws + OFF_LRT);
    float* wcat   = (float*)(ws + OFF_WCAT);
    float* bcat   = (float*)(ws + OFF_BCAT);
    float* scores = (float*)(ws + OFF_SCORES);
    int*   hist   = (int*)(ws + OFF_HIST);
    int*   gcount = (int*)(ws + OFF_GCNT);
    int*   taubin = (int*)(ws + OFF_TAU);
    unsigned long long* gkeys = (unsigned long long*)(ws + OFF_GKEYS);

    concat_w<<<(HDIM * LRLD + 255) / 256, 256, 0, stream>>>(wc, bc, wr, br, wcat, bcat,
                                                            hist, gcount);

    const dim3 tgrid(NROWS / 64, 512 / 64);
    const dim3 ggrid(NROWS / 128, HDIM / 128);   // (256, 4)
    const dim3 ggrid3(NROWS / 128, 1);

    // gemm1 split over K halves (xT half reuses bufA; exact ascending-k fp32 order)
    transpose_half<<<tgrid, 256, 0, stream>>>(x, bufA, 0);
    gemm_nt<<<ggrid, 256, 0, stream>>>(bufA, w1, nullptr, h1T, 512, HDIM, 0, 0);
    transpose_half<<<tgrid, 256, 0, stream>>>(x, bufA, 512);
    gemm_nt<<<ggrid, 256, 0, stream>>>(bufA, w1 + 512 * HDIM, b1, h1T, 512, HDIM, 1, 1);
    // gemm2: h1T -> h2T (bufA free again)
    gemm_nt<<<ggrid, 256, 0, stream>>>(h1T, w2, b2, bufA, 512, HDIM, 0, 1);
    // gemm3: h2T -> lrT
    gemm_nt<<<ggrid3, 256, 0, stream>>>(bufA, wcat, bcat, lrT, 512, LRLD, 0, 0);

    softmax_hist<<<NROWS / 256, 256, 0, stream>>>(lrT, scores, hist);
    select_tau<<<NFRAMES, 1024, 0, stream>>>(hist, taubin);
    gather_cand<<<(NROWS * 10 + 255) / 256, 256, 0, stream>>>(scores, lrT, proposals,
                                                              taubin, gcount, gkeys);
    sort_cand<<<NFRAMES, 1024, 0, stream>>>(gcount, gkeys);
    nms_out<<<NFRAMES, 64, 0, stream>>>(gkeys, gcount, scores, lrT, proposals, out);
}